// Round 15
// baseline (333.414 us; speedup 1.0000x reference)
//
#include <hip/hip_runtime.h>
#include <hip/hip_fp16.h>

#define HDIM 32
#define IN_DIM 128
#define NEG_SLOPE 0.2f
#define NPB 128            // nodes per coarse bucket (power of 2)
#define NPB_SHIFT 7
#define MAXB 1024          // max buckets (B = ceil(N/128) = 782)
#define CHUNK 8192         // edges per chunk block
#define CAP 4096           // max records per bucket for LDS sort fast path

typedef _Float16 half8  __attribute__((ext_vector_type(8)));
typedef _Float16 half4v __attribute__((ext_vector_type(4)));
typedef float    floatx4 __attribute__((ext_vector_type(4)));
typedef float    floatx2 __attribute__((ext_vector_type(2)));

__device__ __forceinline__ float leaky(float e) {
    return (e >= 0.f) ? e : NEG_SLOPE * e;
}

// ------------- MFMA GEMM (layer 1, fp32 in): h8 fp8 + exact fp32 es/ed -----

template<int K>
__global__ __launch_bounds__(256) void gemm_f32in(
    const float* __restrict__ x, const float* __restrict__ W,
    const float* __restrict__ a_s, const float* __restrict__ a_d,
    uint2* __restrict__ h8, float* __restrict__ es, float* __restrict__ ed, int N)
{
    constexpr int KP = K + 8;
    __shared__ _Float16 xs[64 * KP];
    __shared__ _Float16 Wt[32 * KP];          // Wt[n][k] = W[k][n]
    __shared__ float stage[64 * 33];
    const int tid = threadIdx.x;
    for (int i = tid; i < K * 32; i += 256) {
        int k = i >> 5, n = i & 31;
        Wt[n * KP + k] = (_Float16)W[i];
    }
    const int lane = tid & 63;
    const int wave = tid >> 6;
    const int m16  = lane & 15;
    const int quad = lane >> 4;
    const float as0 = a_s[m16], as1 = a_s[m16 + 16];
    const float ad0 = a_d[m16], ad1 = a_d[m16 + 16];

    const int ntiles = (N + 63) >> 6;
    for (int tile = blockIdx.x; tile < ntiles; tile += gridDim.x) {
        const int row0 = tile << 6;
        __syncthreads();
        for (int i = tid; i < 64 * (K / 4); i += 256) {
            int r  = i / (K / 4);
            int c4 = i % (K / 4);
            float4 v = (row0 + r < N) ? ((const float4*)x)[(size_t)(row0 + r) * (K / 4) + c4]
                                      : make_float4(0.f, 0.f, 0.f, 0.f);
            half4v hv = { (_Float16)v.x, (_Float16)v.y, (_Float16)v.z, (_Float16)v.w };
            *(half4v*)&xs[r * KP + c4 * 4] = hv;
        }
        __syncthreads();
        floatx4 acc0 = {0.f, 0.f, 0.f, 0.f}, acc1 = {0.f, 0.f, 0.f, 0.f};
        const int rbase = wave * 16;
        #pragma unroll
        for (int kt = 0; kt < K / 32; kt++) {
            half8 a  = *(half8*)&xs[(rbase + m16) * KP + kt * 32 + quad * 8];
            half8 b0 = *(half8*)&Wt[m16 * KP + kt * 32 + quad * 8];
            half8 b1 = *(half8*)&Wt[(m16 + 16) * KP + kt * 32 + quad * 8];
            acc0 = __builtin_amdgcn_mfma_f32_16x16x32_f16(a, b0, acc0, 0, 0, 0);
            acc1 = __builtin_amdgcn_mfma_f32_16x16x32_f16(a, b1, acc1, 0, 0, 0);
        }
        #pragma unroll
        for (int r = 0; r < 4; r++) {
            const int lr = rbase + quad * 4 + r;
            int row = row0 + lr;
            float c0 = acc0[r], c1 = acc1[r];
            stage[lr * 33 + m16]      = c0;
            stage[lr * 33 + m16 + 16] = c1;
            float ps = c0 * as0 + c1 * as1;
            float pd = c0 * ad0 + c1 * ad1;
            #pragma unroll
            for (int m = 8; m >= 1; m >>= 1) { ps += __shfl_xor(ps, m); pd += __shfl_xor(pd, m); }
            if (row < N && m16 == 0) { es[row] = ps; ed[row] = pd; }
        }
        __syncthreads();
        {
            int r = tid >> 2, seg = tid & 3;
            int row = row0 + r;
            if (row < N) {
                const float* sp = &stage[r * 33 + seg * 8];
                unsigned int u0, u1;
                u0 = __builtin_amdgcn_cvt_pk_fp8_f32(sp[0], sp[1], 0,  false);
                u0 = __builtin_amdgcn_cvt_pk_fp8_f32(sp[2], sp[3], u0, true);
                u1 = __builtin_amdgcn_cvt_pk_fp8_f32(sp[4], sp[5], 0,  false);
                u1 = __builtin_amdgcn_cvt_pk_fp8_f32(sp[6], sp[7], u1, true);
                h8[(size_t)row * 4 + seg] = make_uint2(u0, u1);
            }
        }
    }
}

// ------------- MFMA GEMM (layers 2-4, fp16 in): h8 fp8 + es/ed -------------

__global__ __launch_bounds__(256) void gemm_f16in(
    const __half* __restrict__ y, const float* __restrict__ W,
    const float* __restrict__ a_s, const float* __restrict__ a_d,
    uint2* __restrict__ h8, float* __restrict__ es, float* __restrict__ ed, int N)
{
    constexpr int K = 32, KP = K + 8;
    __shared__ _Float16 xs[64 * KP];
    __shared__ _Float16 Wt[32 * KP];
    __shared__ float stage[64 * 33];
    const int tid = threadIdx.x;
    {
        int i = tid, k = i >> 5, n = i & 31;
        if (i < K * 32) Wt[n * KP + k] = (_Float16)W[i];
        i = tid + 256; k = i >> 5; n = i & 31;
        if (i < K * 32) Wt[n * KP + k] = (_Float16)W[i];
        i = tid + 512; k = i >> 5; n = i & 31;
        if (i < K * 32) Wt[n * KP + k] = (_Float16)W[i];
        i = tid + 768; k = i >> 5; n = i & 31;
        if (i < K * 32) Wt[n * KP + k] = (_Float16)W[i];
    }
    const int lane = tid & 63;
    const int wave = tid >> 6;
    const int m16  = lane & 15;
    const int quad = lane >> 4;
    const float as0 = a_s[m16], as1 = a_s[m16 + 16];
    const float ad0 = a_d[m16], ad1 = a_d[m16 + 16];

    const int ntiles = (N + 63) >> 6;
    for (int tile = blockIdx.x; tile < ntiles; tile += gridDim.x) {
        const int row0 = tile << 6;
        __syncthreads();
        {   // stage 64 rows x 32 halves: 256 x half8, one per thread
            int r = tid >> 2, c8 = tid & 3;
            int row = row0 + r;
            half8 v;
            if (row < N) v = *(const half8*)((const _Float16*)y + (size_t)row * 32 + c8 * 8);
            else { v = (half8)(_Float16)0.f; }
            *(half8*)&xs[r * KP + c8 * 8] = v;
        }
        __syncthreads();
        floatx4 acc0 = {0.f, 0.f, 0.f, 0.f}, acc1 = {0.f, 0.f, 0.f, 0.f};
        const int rbase = wave * 16;
        half8 a  = *(half8*)&xs[(rbase + m16) * KP + quad * 8];
        half8 b0 = *(half8*)&Wt[m16 * KP + quad * 8];
        half8 b1 = *(half8*)&Wt[(m16 + 16) * KP + quad * 8];
        acc0 = __builtin_amdgcn_mfma_f32_16x16x32_f16(a, b0, acc0, 0, 0, 0);
        acc1 = __builtin_amdgcn_mfma_f32_16x16x32_f16(a, b1, acc1, 0, 0, 0);
        #pragma unroll
        for (int r = 0; r < 4; r++) {
            const int lr = rbase + quad * 4 + r;
            int row = row0 + lr;
            float c0 = acc0[r], c1 = acc1[r];
            stage[lr * 33 + m16]      = c0;
            stage[lr * 33 + m16 + 16] = c1;
            float ps = c0 * as0 + c1 * as1;
            float pd = c0 * ad0 + c1 * ad1;
            #pragma unroll
            for (int m = 8; m >= 1; m >>= 1) { ps += __shfl_xor(ps, m); pd += __shfl_xor(pd, m); }
            if (row < N && m16 == 0) { es[row] = ps; ed[row] = pd; }
        }
        __syncthreads();
        {
            int r = tid >> 2, seg = tid & 3;
            int row = row0 + r;
            if (row < N) {
                const float* sp = &stage[r * 33 + seg * 8];
                unsigned int u0, u1;
                u0 = __builtin_amdgcn_cvt_pk_fp8_f32(sp[0], sp[1], 0,  false);
                u0 = __builtin_amdgcn_cvt_pk_fp8_f32(sp[2], sp[3], u0, true);
                u1 = __builtin_amdgcn_cvt_pk_fp8_f32(sp[4], sp[5], 0,  false);
                u1 = __builtin_amdgcn_cvt_pk_fp8_f32(sp[6], sp[7], u1, true);
                h8[(size_t)row * 4 + seg] = make_uint2(u0, u1);
            }
        }
    }
}

// ---------------- Two-level CSR build (once per call) ----------------

__global__ __launch_bounds__(256) void chunk_hist(
    const int* __restrict__ dsts, int E, int B, int* __restrict__ cnt2D)
{
    __shared__ int hist[MAXB];
    const int blk = blockIdx.x;
    for (int i = threadIdx.x; i < B; i += 256) hist[i] = 0;
    __syncthreads();
    const int e0 = blk * CHUNK;
    for (int i = threadIdx.x; i < CHUNK; i += 256) {
        int e = e0 + i;
        if (e < E) atomicAdd(&hist[dsts[e] >> NPB_SHIFT], 1);
    }
    __syncthreads();
    for (int i = threadIdx.x; i < B; i += 256) cnt2D[(size_t)blk * B + i] = hist[i];
}

__global__ __launch_bounds__(256) void chunk_scan(
    const int* __restrict__ cnt2D, int NBLK, int B,
    int* __restrict__ off2D, int* __restrict__ bcnt)
{
    __shared__ int s[256];
    const int b = blockIdx.x, t = threadIdx.x;
    int v = (t < NBLK) ? cnt2D[(size_t)t * B + b] : 0;
    s[t] = v;
    __syncthreads();
    for (int off = 1; off < 256; off <<= 1) {
        int add = (t >= off) ? s[t - off] : 0;
        __syncthreads();
        s[t] += add;
        __syncthreads();
    }
    if (t < NBLK) off2D[(size_t)t * B + b] = s[t] - v;
    if (t == 255) bcnt[b] = s[255];
}

__global__ __launch_bounds__(1024) void bucket_scan(
    const int* __restrict__ bcnt, int B, int E,
    int* __restrict__ bstart, int* __restrict__ rowptr, int N)
{
    __shared__ int s[1024];
    const int t = threadIdx.x;
    int v = (t < B) ? bcnt[t] : 0;
    s[t] = v;
    __syncthreads();
    for (int off = 1; off < 1024; off <<= 1) {
        int add = (t >= off) ? s[t - off] : 0;
        __syncthreads();
        s[t] += add;
        __syncthreads();
    }
    if (t < B) bstart[t] = s[t] - v;
    if (t == 0) { bstart[B] = E; rowptr[N] = E; }
}

__global__ __launch_bounds__(256) void pair_scatter2(
    const int* __restrict__ srcs, const int* __restrict__ dsts, int E, int B,
    const int* __restrict__ off2D, const int* __restrict__ bstart,
    int* __restrict__ pairs)
{
    __shared__ int cur[MAXB];
    const int blk = blockIdx.x;
    for (int i = threadIdx.x; i < B; i += 256)
        cur[i] = bstart[i] + off2D[(size_t)blk * B + i];
    __syncthreads();
    const int e0 = blk * CHUNK;
    for (int i = threadIdx.x; i < CHUNK; i += 256) {
        int e = e0 + i;
        if (e < E) {
            int s = srcs[e], d = dsts[e];
            int pos = atomicAdd(&cur[d >> NPB_SHIFT], 1);
            pairs[pos] = (s << NPB_SHIFT) | (d & (NPB - 1));
        }
    }
}

__global__ __launch_bounds__(256) void bucket_sort(
    const int* __restrict__ pairs, const int* __restrict__ bstart,
    int* __restrict__ rowptr, int* __restrict__ csrsrc, int N)
{
    __shared__ int ldeg[NPB];
    __shared__ int lex[NPB];
    __shared__ int recs[CAP];
    __shared__ int sorted[CAP];
    const int b = blockIdx.x, t = threadIdx.x;
    const int p0 = bstart[b], p1 = bstart[b + 1];
    const int cnt = p1 - p0;
    if (t < NPB) ldeg[t] = 0;
    __syncthreads();
    for (int i = t; i < cnt; i += 256) {
        int r = pairs[p0 + i];
        atomicAdd(&ldeg[r & (NPB - 1)], 1);
        if (i < CAP) recs[i] = r;
    }
    __syncthreads();
    if (t < NPB) lex[t] = ldeg[t];
    __syncthreads();
    for (int off = 1; off < NPB; off <<= 1) {
        int add = (t >= off && t < NPB) ? lex[t - off] : 0;
        __syncthreads();
        if (t < NPB) lex[t] += add;
        __syncthreads();
    }
    const int node0 = b * NPB;
    if (t < NPB) {
        int excl = lex[t] - ldeg[t];
        if (node0 + t < N) rowptr[node0 + t] = p0 + excl;
        ldeg[t] = excl;
    }
    __syncthreads();
    if (cnt <= CAP) {
        for (int i = t; i < cnt; i += 256) {
            int r = recs[i];
            int pos = atomicAdd(&ldeg[r & (NPB - 1)], 1);
            sorted[pos] = r >> NPB_SHIFT;
        }
        __syncthreads();
        for (int i = t; i < cnt; i += 256) csrsrc[p0 + i] = sorted[i];
    } else {
        for (int i = t; i < cnt; i += 256) {
            int r = pairs[p0 + i];
            int pos = atomicAdd(&ldeg[r & (NPB - 1)], 1);
            csrsrc[p0 + pos] = r >> NPB_SHIFT;
        }
    }
}

// -------- Aggregation: 2 lanes/node, uint4 fp8 gather, fp16/fp32 out -------

__device__ __forceinline__ void acc16(float* acc, uint4 u, float w) {
    floatx2 f0 = __builtin_amdgcn_cvt_pk_f32_fp8(u.x, false);
    floatx2 f1 = __builtin_amdgcn_cvt_pk_f32_fp8(u.x, true);
    floatx2 f2 = __builtin_amdgcn_cvt_pk_f32_fp8(u.y, false);
    floatx2 f3 = __builtin_amdgcn_cvt_pk_f32_fp8(u.y, true);
    floatx2 f4 = __builtin_amdgcn_cvt_pk_f32_fp8(u.z, false);
    floatx2 f5 = __builtin_amdgcn_cvt_pk_f32_fp8(u.z, true);
    floatx2 f6 = __builtin_amdgcn_cvt_pk_f32_fp8(u.w, false);
    floatx2 f7 = __builtin_amdgcn_cvt_pk_f32_fp8(u.w, true);
    acc[0]  += w * f0.x; acc[1]  += w * f0.y; acc[2]  += w * f1.x; acc[3]  += w * f1.y;
    acc[4]  += w * f2.x; acc[5]  += w * f2.y; acc[6]  += w * f3.x; acc[7]  += w * f3.y;
    acc[8]  += w * f4.x; acc[9]  += w * f4.y; acc[10] += w * f5.x; acc[11] += w * f5.y;
    acc[12] += w * f6.x; acc[13] += w * f6.y; acc[14] += w * f7.x; acc[15] += w * f7.y;
}

template<bool LAST>
__global__ __launch_bounds__(256) void agg8(
    const uint4* __restrict__ h8, const float* __restrict__ es, const float* __restrict__ ed,
    const int* __restrict__ rowptr, const int* __restrict__ csrsrc,
    const float* __restrict__ b, __half* __restrict__ y16, float* __restrict__ out, int N)
{
    const int gid  = blockIdx.x * 256 + threadIdx.x;
    const int node = gid >> 1;
    const int l    = threadIdx.x & 1;
    if (node >= N) return;

    const int e0 = rowptr[node];
    const int e1 = rowptr[node + 1];
    const float edi = ed[node];

    float acc[16];
    #pragma unroll
    for (int i = 0; i < 16; i++) acc[i] = 0.f;
    float den = 0.f;

    int e = e0;
    for (; e + 8 <= e1; e += 8) {
        int s[8]; float q[8]; uint4 u[8];
        #pragma unroll
        for (int j = 0; j < 8; j++) s[j] = csrsrc[e + j];
        #pragma unroll
        for (int j = 0; j < 8; j++) q[j] = es[s[j]];
        #pragma unroll
        for (int j = 0; j < 8; j++) u[j] = h8[(size_t)s[j] * 2 + l];
        #pragma unroll
        for (int j = 0; j < 8; j++) {
            float w = __expf(leaky(q[j] + edi));
            den += w;
            acc16(acc, u[j], w);
        }
    }
    for (; e < e1; e++) {
        int s = csrsrc[e];
        float w = __expf(leaky(es[s] + edi));
        uint4 u = h8[(size_t)s * 2 + l];
        den += w;
        acc16(acc, u, w);
    }
    {   // self-loop
        float w = __expf(leaky(es[node] + edi));
        uint4 u = h8[(size_t)node * 2 + l];
        den += w;
        acc16(acc, u, w);
    }

    const float4* b4 = (const float4*)b;
    float inv = 1.f / den;
    float o[16];
    #pragma unroll
    for (int g = 0; g < 4; g++) {
        float4 bv = b4[l * 4 + g];
        o[g*4+0] = acc[g*4+0] * inv + bv.x;
        o[g*4+1] = acc[g*4+1] * inv + bv.y;
        o[g*4+2] = acc[g*4+2] * inv + bv.z;
        o[g*4+3] = acc[g*4+3] * inv + bv.w;
    }

    if (LAST) {
        float4* op = (float4*)out + (size_t)node * 8 + l * 4;
        #pragma unroll
        for (int g = 0; g < 4; g++) {
            float4 v = { o[g*4+0], o[g*4+1], o[g*4+2], o[g*4+3] };
            op[g] = v;
        }
    } else {
        _Float16* yp = (_Float16*)y16 + (size_t)node * 32 + l * 16;
        half8 v0 = { (_Float16)o[0], (_Float16)o[1], (_Float16)o[2], (_Float16)o[3],
                     (_Float16)o[4], (_Float16)o[5], (_Float16)o[6], (_Float16)o[7] };
        half8 v1 = { (_Float16)o[8], (_Float16)o[9], (_Float16)o[10], (_Float16)o[11],
                     (_Float16)o[12], (_Float16)o[13], (_Float16)o[14], (_Float16)o[15] };
        *(half8*)yp = v0;
        *(half8*)(yp + 8) = v1;
    }
}

// -------- Pool: one 64-lane wave per graph (batch sorted, binary search) ---

__global__ __launch_bounds__(256) void pool_graph(
    const float* __restrict__ x, const int* __restrict__ batch,
    float* __restrict__ out, int N, int G)
{
    const int g = (blockIdx.x * 256 + threadIdx.x) >> 6;
    if (g >= G) return;
    const int lane = threadIdx.x & 63;
    const int feat = lane & 31;
    const int half = lane >> 5;

    int lo = 0, hi = N;
    while (lo < hi) { int mid = (lo + hi) >> 1; if (batch[mid] < g) lo = mid + 1; else hi = mid; }
    const int start = lo;
    int lo2 = start, hi2 = N;
    while (lo2 < hi2) { int mid = (lo2 + hi2) >> 1; if (batch[mid] < g + 1) lo2 = mid + 1; else hi2 = mid; }
    const int end = lo2;

    float acc = 0.f;
    for (int i = start + half; i < end; i += 2)
        acc += x[(size_t)i * HDIM + feat];
    acc += __shfl_xor(acc, 32);
    if (half == 0) {
        float cnt = (float)(end - start);
        out[(size_t)g * HDIM + feat] = acc / fmaxf(cnt, 1.f);
    }
}

// ---------------- Launch ----------------

extern "C" void kernel_launch(void* const* d_in, const int* in_sizes, int n_in,
                              void* d_out, int out_size, void* d_ws, size_t ws_size,
                              hipStream_t stream) {
    const float* x          = (const float*)d_in[0];
    const int*   edge_index = (const int*)d_in[1];
    const int*   batch      = (const int*)d_in[2];

    const int N = in_sizes[2];              // 100000
    const int E = in_sizes[1] / 2;          // 1600000
    const int G = out_size / HDIM;          // 2048
    const int B = (N + NPB - 1) / NPB;      // 782 buckets
    const int NBLK = (E + CHUNK - 1) / CHUNK;
    const int ntiles = (N + 63) / 64;

    const int* srcs = edge_index;
    const int* dsts = edge_index + E;

    // workspace layout (16B-aligned offsets)
    char* p = (char*)d_ws;
    uint2* h8     = (uint2*)p; p += (size_t)N * 4 * sizeof(uint2);   // fp8 rows, 32 B
    __half* y16   = (__half*)p; p += (size_t)N * HDIM * sizeof(__half); // fp16 interlayer
    float* xbuf   = (float*)p; p += (size_t)N * HDIM * sizeof(float);   // fp32 final
    float* es     = (float*)p; p += (size_t)N * sizeof(float);
    float* ed     = (float*)p; p += (size_t)N * sizeof(float);
    int*   rowptr = (int*)p;   p += (size_t)(N + 1) * sizeof(int);
    p += 16 - ((size_t)p & 15);
    int*   csrsrc = (int*)p;   p += (size_t)E * sizeof(int);
    int*   pairs  = (int*)p;   p += (size_t)E * sizeof(int);
    int*   cnt2D  = (int*)p;   p += (size_t)NBLK * B * sizeof(int);
    int*   off2D  = (int*)p;   p += (size_t)NBLK * B * sizeof(int);
    int*   bcnt   = (int*)p;   p += (size_t)B * sizeof(int);
    int*   bstart = (int*)p;   p += (size_t)(B + 1) * sizeof(int);

    // ---- CSR build (once; same edge set for all 4 layers) ----
    chunk_hist  <<<NBLK, 256, 0, stream>>>(dsts, E, B, cnt2D);
    chunk_scan  <<<B, 256, 0, stream>>>(cnt2D, NBLK, B, off2D, bcnt);
    bucket_scan <<<1, 1024, 0, stream>>>(bcnt, B, E, bstart, rowptr, N);
    pair_scatter2<<<NBLK, 256, 0, stream>>>(srcs, dsts, E, B, off2D, bstart, pairs);
    bucket_sort <<<B, 256, 0, stream>>>(pairs, bstart, rowptr, csrsrc, N);

    const int aggGrid = (N * 2 + 255) / 256;

    // ---- 4 GAT layers ----
    for (int l = 0; l < 4; l++) {
        const float* W   = (const float*)d_in[3 + 4 * l];
        const float* a_s = (const float*)d_in[4 + 4 * l];
        const float* a_d = (const float*)d_in[5 + 4 * l];
        const float* bb  = (const float*)d_in[6 + 4 * l];

        if (l == 0) gemm_f32in<IN_DIM><<<ntiles, 256, 0, stream>>>(x, W, a_s, a_d, h8, es, ed, N);
        else        gemm_f16in<<<ntiles, 256, 0, stream>>>(y16, W, a_s, a_d, h8, es, ed, N);

        if (l < 3)  agg8<false><<<aggGrid, 256, 0, stream>>>((const uint4*)h8, es, ed, rowptr, csrsrc, bb, y16, xbuf, N);
        else        agg8<true> <<<aggGrid, 256, 0, stream>>>((const uint4*)h8, es, ed, rowptr, csrsrc, bb, y16, xbuf, N);
    }

    // ---- global mean pool: one wave per graph ----
    pool_graph<<<(G * 64 + 255) / 256, 256, 0, stream>>>(xbuf, batch, (float*)d_out, N, G);
}

// Round 16
// 311.417 us; speedup vs baseline: 1.0706x; 1.0706x over previous
//
#include <hip/hip_runtime.h>
#include <hip/hip_fp16.h>

#define HDIM 32
#define IN_DIM 128
#define NEG_SLOPE 0.2f
#define NPB 128            // nodes per coarse bucket (power of 2)
#define NPB_SHIFT 7
#define MAXB 1024          // max buckets (B = ceil(N/128) = 782)
#define CHUNK 8192         // edges per chunk block
#define CAP 4096           // max records per bucket for LDS sort fast path

typedef _Float16 half8  __attribute__((ext_vector_type(8)));
typedef _Float16 half4v __attribute__((ext_vector_type(4)));
typedef float    floatx4 __attribute__((ext_vector_type(4)));
typedef float    floatx2 __attribute__((ext_vector_type(2)));

__device__ __forceinline__ float leaky(float e) {
    return (e >= 0.f) ? e : NEG_SLOPE * e;
}

// ------------- MFMA GEMM (layer 1, fp32 in): h8 fp8 + exact fp32 es/ed -----

template<int K>
__global__ __launch_bounds__(256) void gemm_f32in(
    const float* __restrict__ x, const float* __restrict__ W,
    const float* __restrict__ a_s, const float* __restrict__ a_d,
    uint2* __restrict__ h8, float* __restrict__ es, float* __restrict__ ed, int N)
{
    constexpr int KP = K + 8;
    __shared__ _Float16 xs[64 * KP];
    __shared__ _Float16 Wt[32 * KP];          // Wt[n][k] = W[k][n]
    __shared__ float stage[64 * 33];
    const int tid = threadIdx.x;
    for (int i = tid; i < K * 32; i += 256) {
        int k = i >> 5, n = i & 31;
        Wt[n * KP + k] = (_Float16)W[i];
    }
    const int lane = tid & 63;
    const int wave = tid >> 6;
    const int m16  = lane & 15;
    const int quad = lane >> 4;
    const float as0 = a_s[m16], as1 = a_s[m16 + 16];
    const float ad0 = a_d[m16], ad1 = a_d[m16 + 16];

    const int ntiles = (N + 63) >> 6;
    for (int tile = blockIdx.x; tile < ntiles; tile += gridDim.x) {
        const int row0 = tile << 6;
        __syncthreads();
        for (int i = tid; i < 64 * (K / 4); i += 256) {
            int r  = i / (K / 4);
            int c4 = i % (K / 4);
            float4 v = (row0 + r < N) ? ((const float4*)x)[(size_t)(row0 + r) * (K / 4) + c4]
                                      : make_float4(0.f, 0.f, 0.f, 0.f);
            half4v hv = { (_Float16)v.x, (_Float16)v.y, (_Float16)v.z, (_Float16)v.w };
            *(half4v*)&xs[r * KP + c4 * 4] = hv;
        }
        __syncthreads();
        floatx4 acc0 = {0.f, 0.f, 0.f, 0.f}, acc1 = {0.f, 0.f, 0.f, 0.f};
        const int rbase = wave * 16;
        #pragma unroll
        for (int kt = 0; kt < K / 32; kt++) {
            half8 a  = *(half8*)&xs[(rbase + m16) * KP + kt * 32 + quad * 8];
            half8 b0 = *(half8*)&Wt[m16 * KP + kt * 32 + quad * 8];
            half8 b1 = *(half8*)&Wt[(m16 + 16) * KP + kt * 32 + quad * 8];
            acc0 = __builtin_amdgcn_mfma_f32_16x16x32_f16(a, b0, acc0, 0, 0, 0);
            acc1 = __builtin_amdgcn_mfma_f32_16x16x32_f16(a, b1, acc1, 0, 0, 0);
        }
        #pragma unroll
        for (int r = 0; r < 4; r++) {
            const int lr = rbase + quad * 4 + r;
            int row = row0 + lr;
            float c0 = acc0[r], c1 = acc1[r];
            stage[lr * 33 + m16]      = c0;
            stage[lr * 33 + m16 + 16] = c1;
            float ps = c0 * as0 + c1 * as1;
            float pd = c0 * ad0 + c1 * ad1;
            #pragma unroll
            for (int m = 8; m >= 1; m >>= 1) { ps += __shfl_xor(ps, m); pd += __shfl_xor(pd, m); }
            if (row < N && m16 == 0) { es[row] = ps; ed[row] = pd; }
        }
        __syncthreads();
        {
            int r = tid >> 2, seg = tid & 3;
            int row = row0 + r;
            if (row < N) {
                const float* sp = &stage[r * 33 + seg * 8];
                unsigned int u0, u1;
                u0 = __builtin_amdgcn_cvt_pk_fp8_f32(sp[0], sp[1], 0,  false);
                u0 = __builtin_amdgcn_cvt_pk_fp8_f32(sp[2], sp[3], u0, true);
                u1 = __builtin_amdgcn_cvt_pk_fp8_f32(sp[4], sp[5], 0,  false);
                u1 = __builtin_amdgcn_cvt_pk_fp8_f32(sp[6], sp[7], u1, true);
                h8[(size_t)row * 4 + seg] = make_uint2(u0, u1);
            }
        }
    }
}

// ---------------- Two-level CSR build (once per call) ----------------

__global__ __launch_bounds__(256) void chunk_hist(
    const int* __restrict__ dsts, int E, int B, int* __restrict__ cnt2D)
{
    __shared__ int hist[MAXB];
    const int blk = blockIdx.x;
    for (int i = threadIdx.x; i < B; i += 256) hist[i] = 0;
    __syncthreads();
    const int e0 = blk * CHUNK;
    for (int i = threadIdx.x; i < CHUNK; i += 256) {
        int e = e0 + i;
        if (e < E) atomicAdd(&hist[dsts[e] >> NPB_SHIFT], 1);
    }
    __syncthreads();
    for (int i = threadIdx.x; i < B; i += 256) cnt2D[(size_t)blk * B + i] = hist[i];
}

__global__ __launch_bounds__(256) void chunk_scan(
    const int* __restrict__ cnt2D, int NBLK, int B,
    int* __restrict__ off2D, int* __restrict__ bcnt)
{
    __shared__ int s[256];
    const int b = blockIdx.x, t = threadIdx.x;
    int v = (t < NBLK) ? cnt2D[(size_t)t * B + b] : 0;
    s[t] = v;
    __syncthreads();
    for (int off = 1; off < 256; off <<= 1) {
        int add = (t >= off) ? s[t - off] : 0;
        __syncthreads();
        s[t] += add;
        __syncthreads();
    }
    if (t < NBLK) off2D[(size_t)t * B + b] = s[t] - v;
    if (t == 255) bcnt[b] = s[255];
}

__global__ __launch_bounds__(1024) void bucket_scan(
    const int* __restrict__ bcnt, int B, int E,
    int* __restrict__ bstart, int* __restrict__ rowptr, int N)
{
    __shared__ int s[1024];
    const int t = threadIdx.x;
    int v = (t < B) ? bcnt[t] : 0;
    s[t] = v;
    __syncthreads();
    for (int off = 1; off < 1024; off <<= 1) {
        int add = (t >= off) ? s[t - off] : 0;
        __syncthreads();
        s[t] += add;
        __syncthreads();
    }
    if (t < B) bstart[t] = s[t] - v;
    if (t == 0) { bstart[B] = E; rowptr[N] = E; }
}

__global__ __launch_bounds__(256) void pair_scatter2(
    const int* __restrict__ srcs, const int* __restrict__ dsts, int E, int B,
    const int* __restrict__ off2D, const int* __restrict__ bstart,
    int* __restrict__ pairs)
{
    __shared__ int cur[MAXB];
    const int blk = blockIdx.x;
    for (int i = threadIdx.x; i < B; i += 256)
        cur[i] = bstart[i] + off2D[(size_t)blk * B + i];
    __syncthreads();
    const int e0 = blk * CHUNK;
    for (int i = threadIdx.x; i < CHUNK; i += 256) {
        int e = e0 + i;
        if (e < E) {
            int s = srcs[e], d = dsts[e];
            int pos = atomicAdd(&cur[d >> NPB_SHIFT], 1);
            pairs[pos] = (s << NPB_SHIFT) | (d & (NPB - 1));
        }
    }
}

__global__ __launch_bounds__(256) void bucket_sort(
    const int* __restrict__ pairs, const int* __restrict__ bstart,
    int* __restrict__ rowptr, int* __restrict__ csrsrc, int N)
{
    __shared__ int ldeg[NPB];
    __shared__ int lex[NPB];
    __shared__ int recs[CAP];
    __shared__ int sorted[CAP];
    const int b = blockIdx.x, t = threadIdx.x;
    const int p0 = bstart[b], p1 = bstart[b + 1];
    const int cnt = p1 - p0;
    if (t < NPB) ldeg[t] = 0;
    __syncthreads();
    for (int i = t; i < cnt; i += 256) {
        int r = pairs[p0 + i];
        atomicAdd(&ldeg[r & (NPB - 1)], 1);
        if (i < CAP) recs[i] = r;
    }
    __syncthreads();
    if (t < NPB) lex[t] = ldeg[t];
    __syncthreads();
    for (int off = 1; off < NPB; off <<= 1) {
        int add = (t >= off && t < NPB) ? lex[t - off] : 0;
        __syncthreads();
        if (t < NPB) lex[t] += add;
        __syncthreads();
    }
    const int node0 = b * NPB;
    if (t < NPB) {
        int excl = lex[t] - ldeg[t];
        if (node0 + t < N) rowptr[node0 + t] = p0 + excl;
        ldeg[t] = excl;
    }
    __syncthreads();
    if (cnt <= CAP) {
        for (int i = t; i < cnt; i += 256) {
            int r = recs[i];
            int pos = atomicAdd(&ldeg[r & (NPB - 1)], 1);
            sorted[pos] = r >> NPB_SHIFT;
        }
        __syncthreads();
        for (int i = t; i < cnt; i += 256) csrsrc[p0 + i] = sorted[i];
    } else {
        for (int i = t; i < cnt; i += 256) {
            int r = pairs[p0 + i];
            int pos = atomicAdd(&ldeg[r & (NPB - 1)], 1);
            csrsrc[p0 + pos] = r >> NPB_SHIFT;
        }
    }
}

// -------- Fused agg + next-layer MFMA GEMM ---------------------------------
// 2 lanes/node, 128 nodes/block. Edge loop identical to R14/R15. For !LAST:
// block stages its 128 fp16 out-rows in LDS, runs the 32x32 next-layer GEMM
// on matrix cores (4 MFMA/wave), computes exact es/ed from fp32 accumulators,
// packs fp8 h for the next layer. Ping-pong buffers (no cross-block hazard).

__device__ __forceinline__ void acc16(float* acc, uint4 u, float w) {
    floatx2 f0 = __builtin_amdgcn_cvt_pk_f32_fp8(u.x, false);
    floatx2 f1 = __builtin_amdgcn_cvt_pk_f32_fp8(u.x, true);
    floatx2 f2 = __builtin_amdgcn_cvt_pk_f32_fp8(u.y, false);
    floatx2 f3 = __builtin_amdgcn_cvt_pk_f32_fp8(u.y, true);
    floatx2 f4 = __builtin_amdgcn_cvt_pk_f32_fp8(u.z, false);
    floatx2 f5 = __builtin_amdgcn_cvt_pk_f32_fp8(u.z, true);
    floatx2 f6 = __builtin_amdgcn_cvt_pk_f32_fp8(u.w, false);
    floatx2 f7 = __builtin_amdgcn_cvt_pk_f32_fp8(u.w, true);
    acc[0]  += w * f0.x; acc[1]  += w * f0.y; acc[2]  += w * f1.x; acc[3]  += w * f1.y;
    acc[4]  += w * f2.x; acc[5]  += w * f2.y; acc[6]  += w * f3.x; acc[7]  += w * f3.y;
    acc[8]  += w * f4.x; acc[9]  += w * f4.y; acc[10] += w * f5.x; acc[11] += w * f5.y;
    acc[12] += w * f6.x; acc[13] += w * f6.y; acc[14] += w * f7.x; acc[15] += w * f7.y;
}

template<bool LAST>
__global__ __launch_bounds__(256) void agg_mfma(
    const uint4* __restrict__ h8in, const float* __restrict__ es, const float* __restrict__ ed,
    const int* __restrict__ rowptr, const int* __restrict__ csrsrc,
    const float* __restrict__ b,
    const float* __restrict__ Wn, const float* __restrict__ as_n, const float* __restrict__ ad_n,
    uint4* __restrict__ h8out, float* __restrict__ es_out, float* __restrict__ ed_out,
    float* __restrict__ out, int N)
{
    constexpr int KP = 40;                    // 32 + 8 pad
    __shared__ _Float16 xs[128 * KP];         // 10 KB fp16 out rows
    __shared__ _Float16 Wt[32 * KP];          // 2.5 KB
    __shared__ float stage[128 * 33];         // 16.9 KB
    const int tid = threadIdx.x;
    if (!LAST) {
        for (int i = tid; i < 32 * 32; i += 256) {
            int k = i >> 5, n = i & 31;
            Wt[n * KP + k] = (_Float16)Wn[i];
        }
    }
    const int node0 = blockIdx.x * 128;
    const int li    = tid >> 1;
    const int node  = node0 + li;
    const int l     = tid & 1;
    const bool valid = node < N;

    float acc[16];
    #pragma unroll
    for (int i = 0; i < 16; i++) acc[i] = 0.f;
    float den = 0.f;
    float o[16];

    if (valid) {
        const int e0 = rowptr[node];
        const int e1 = rowptr[node + 1];
        const float edi = ed[node];
        int e = e0;
        for (; e + 8 <= e1; e += 8) {
            int s[8]; float q[8]; uint4 u[8];
            #pragma unroll
            for (int j = 0; j < 8; j++) s[j] = csrsrc[e + j];
            #pragma unroll
            for (int j = 0; j < 8; j++) q[j] = es[s[j]];
            #pragma unroll
            for (int j = 0; j < 8; j++) u[j] = h8in[(size_t)s[j] * 2 + l];
            #pragma unroll
            for (int j = 0; j < 8; j++) {
                float w = __expf(leaky(q[j] + edi));
                den += w;
                acc16(acc, u[j], w);
            }
        }
        for (; e < e1; e++) {
            int s = csrsrc[e];
            float w = __expf(leaky(es[s] + edi));
            uint4 u = h8in[(size_t)s * 2 + l];
            den += w;
            acc16(acc, u, w);
        }
        {   // self-loop
            float w = __expf(leaky(es[node] + edi));
            uint4 u = h8in[(size_t)node * 2 + l];
            den += w;
            acc16(acc, u, w);
        }
        const float4* b4 = (const float4*)b;
        float inv = 1.f / den;
        #pragma unroll
        for (int g = 0; g < 4; g++) {
            float4 bv = b4[l * 4 + g];
            o[g*4+0] = acc[g*4+0] * inv + bv.x;
            o[g*4+1] = acc[g*4+1] * inv + bv.y;
            o[g*4+2] = acc[g*4+2] * inv + bv.z;
            o[g*4+3] = acc[g*4+3] * inv + bv.w;
        }
    }

    if (LAST) {
        if (valid) {
            float4* op = (float4*)out + (size_t)node * 8 + l * 4;
            #pragma unroll
            for (int g = 0; g < 4; g++) {
                float4 v = { o[g*4+0], o[g*4+1], o[g*4+2], o[g*4+3] };
                op[g] = v;
            }
        }
        return;
    }

    // stage out rows fp16 in LDS (zeros for invalid rows)
    {
        _Float16* xp = &xs[li * KP + l * 16];
        half8 v0, v1;
        if (valid) {
            v0 = (half8){ (_Float16)o[0], (_Float16)o[1], (_Float16)o[2], (_Float16)o[3],
                          (_Float16)o[4], (_Float16)o[5], (_Float16)o[6], (_Float16)o[7] };
            v1 = (half8){ (_Float16)o[8], (_Float16)o[9], (_Float16)o[10], (_Float16)o[11],
                          (_Float16)o[12], (_Float16)o[13], (_Float16)o[14], (_Float16)o[15] };
        } else {
            v0 = (half8)(_Float16)0.f;
            v1 = (half8)(_Float16)0.f;
        }
        *(half8*)xp = v0;
        *(half8*)(xp + 8) = v1;
    }
    __syncthreads();

    // block-level MFMA: h' = out @ Wn, es/ed from fp32 accumulators
    {
        const int lane = tid & 63, wave = tid >> 6;
        const int m16 = lane & 15, quad = lane >> 4;
        const float as0 = as_n[m16], as1 = as_n[m16 + 16];
        const float ad0 = ad_n[m16], ad1 = ad_n[m16 + 16];
        #pragma unroll
        for (int rt = 0; rt < 2; rt++) {
            const int rb = wave * 32 + rt * 16;
            half8 a  = *(half8*)&xs[(rb + m16) * KP + quad * 8];
            half8 b0 = *(half8*)&Wt[m16 * KP + quad * 8];
            half8 b1 = *(half8*)&Wt[(m16 + 16) * KP + quad * 8];
            floatx4 c0 = {0.f,0.f,0.f,0.f}, c1 = {0.f,0.f,0.f,0.f};
            c0 = __builtin_amdgcn_mfma_f32_16x16x32_f16(a, b0, c0, 0, 0, 0);
            c1 = __builtin_amdgcn_mfma_f32_16x16x32_f16(a, b1, c1, 0, 0, 0);
            #pragma unroll
            for (int r = 0; r < 4; r++) {
                const int lr = rb + quad * 4 + r;
                int row = node0 + lr;
                float v0 = c0[r], v1 = c1[r];
                stage[lr * 33 + m16]      = v0;
                stage[lr * 33 + m16 + 16] = v1;
                float ps = v0 * as0 + v1 * as1;
                float pd = v0 * ad0 + v1 * ad1;
                #pragma unroll
                for (int m = 8; m >= 1; m >>= 1) { ps += __shfl_xor(ps, m); pd += __shfl_xor(pd, m); }
                if (row < N && m16 == 0) { es_out[row] = ps; ed_out[row] = pd; }
            }
        }
    }
    __syncthreads();

    // pack fp8: 256 threads -> 128 rows x 2 segs of 16 values (uint4)
    {
        int r = tid >> 1, seg = tid & 1;
        int row = node0 + r;
        if (row < N) {
            const float* sp = &stage[r * 33 + seg * 16];
            unsigned int u0, u1, u2, u3;
            u0 = __builtin_amdgcn_cvt_pk_fp8_f32(sp[0],  sp[1],  0,  false);
            u0 = __builtin_amdgcn_cvt_pk_fp8_f32(sp[2],  sp[3],  u0, true);
            u1 = __builtin_amdgcn_cvt_pk_fp8_f32(sp[4],  sp[5],  0,  false);
            u1 = __builtin_amdgcn_cvt_pk_fp8_f32(sp[6],  sp[7],  u1, true);
            u2 = __builtin_amdgcn_cvt_pk_fp8_f32(sp[8],  sp[9],  0,  false);
            u2 = __builtin_amdgcn_cvt_pk_fp8_f32(sp[10], sp[11], u2, true);
            u3 = __builtin_amdgcn_cvt_pk_fp8_f32(sp[12], sp[13], 0,  false);
            u3 = __builtin_amdgcn_cvt_pk_fp8_f32(sp[14], sp[15], u3, true);
            uint4 v = { u0, u1, u2, u3 };
            h8out[(size_t)row * 2 + seg] = v;
        }
    }
}

// -------- Pool: one 64-lane wave per graph (batch sorted, binary search) ---

__global__ __launch_bounds__(256) void pool_graph(
    const float* __restrict__ x, const int* __restrict__ batch,
    float* __restrict__ out, int N, int G)
{
    const int g = (blockIdx.x * 256 + threadIdx.x) >> 6;
    if (g >= G) return;
    const int lane = threadIdx.x & 63;
    const int feat = lane & 31;
    const int half = lane >> 5;

    int lo = 0, hi = N;
    while (lo < hi) { int mid = (lo + hi) >> 1; if (batch[mid] < g) lo = mid + 1; else hi = mid; }
    const int start = lo;
    int lo2 = start, hi2 = N;
    while (lo2 < hi2) { int mid = (lo2 + hi2) >> 1; if (batch[mid] < g + 1) lo2 = mid + 1; else hi2 = mid; }
    const int end = lo2;

    float acc = 0.f;
    for (int i = start + half; i < end; i += 2)
        acc += x[(size_t)i * HDIM + feat];
    acc += __shfl_xor(acc, 32);
    if (half == 0) {
        float cnt = (float)(end - start);
        out[(size_t)g * HDIM + feat] = acc / fmaxf(cnt, 1.f);
    }
}

// ---------------- Launch ----------------

extern "C" void kernel_launch(void* const* d_in, const int* in_sizes, int n_in,
                              void* d_out, int out_size, void* d_ws, size_t ws_size,
                              hipStream_t stream) {
    const float* x          = (const float*)d_in[0];
    const int*   edge_index = (const int*)d_in[1];
    const int*   batch      = (const int*)d_in[2];

    const int N = in_sizes[2];              // 100000
    const int E = in_sizes[1] / 2;          // 1600000
    const int G = out_size / HDIM;          // 2048
    const int B = (N + NPB - 1) / NPB;      // 782 buckets
    const int NBLK = (E + CHUNK - 1) / CHUNK;
    const int ntiles = (N + 63) / 64;

    const int* srcs = edge_index;
    const int* dsts = edge_index + E;

    // workspace layout (16B-aligned offsets)
    char* p = (char*)d_ws;
    uint4* h8a    = (uint4*)p; p += (size_t)N * 2 * sizeof(uint4);   // fp8 rows, 32 B
    uint4* h8b    = (uint4*)p; p += (size_t)N * 2 * sizeof(uint4);
    float* xbuf   = (float*)p; p += (size_t)N * HDIM * sizeof(float);
    float* esa    = (float*)p; p += (size_t)N * sizeof(float);
    float* eda    = (float*)p; p += (size_t)N * sizeof(float);
    float* esb    = (float*)p; p += (size_t)N * sizeof(float);
    float* edb    = (float*)p; p += (size_t)N * sizeof(float);
    int*   rowptr = (int*)p;   p += (size_t)(N + 1) * sizeof(int);
    p += 16 - ((size_t)p & 15);
    int*   csrsrc = (int*)p;   p += (size_t)E * sizeof(int);
    int*   pairs  = (int*)p;   p += (size_t)E * sizeof(int);
    int*   cnt2D  = (int*)p;   p += (size_t)NBLK * B * sizeof(int);
    int*   off2D  = (int*)p;   p += (size_t)NBLK * B * sizeof(int);
    int*   bcnt   = (int*)p;   p += (size_t)B * sizeof(int);
    int*   bstart = (int*)p;   p += (size_t)(B + 1) * sizeof(int);

    // ---- CSR build (once; same edge set for all 4 layers) ----
    chunk_hist  <<<NBLK, 256, 0, stream>>>(dsts, E, B, cnt2D);
    chunk_scan  <<<B, 256, 0, stream>>>(cnt2D, NBLK, B, off2D, bcnt);
    bucket_scan <<<1, 1024, 0, stream>>>(bcnt, B, E, bstart, rowptr, N);
    pair_scatter2<<<NBLK, 256, 0, stream>>>(srcs, dsts, E, B, off2D, bstart, pairs);
    bucket_sort <<<B, 256, 0, stream>>>(pairs, bstart, rowptr, csrsrc, N);

    const float* W1  = (const float*)d_in[3];
    const float* as1 = (const float*)d_in[4];
    const float* ad1 = (const float*)d_in[5];
    const float* b1  = (const float*)d_in[6];
    const float* W2  = (const float*)d_in[7];
    const float* as2 = (const float*)d_in[8];
    const float* ad2 = (const float*)d_in[9];
    const float* b2  = (const float*)d_in[10];
    const float* W3  = (const float*)d_in[11];
    const float* as3 = (const float*)d_in[12];
    const float* ad3 = (const float*)d_in[13];
    const float* b3  = (const float*)d_in[14];
    const float* W4  = (const float*)d_in[15];
    const float* as4 = (const float*)d_in[16];
    const float* ad4 = (const float*)d_in[17];
    const float* b4  = (const float*)d_in[18];

    const int aggGrid = (N + 127) / 128;

    // layer 1 GEMM, then 4 fused agg(+next-layer MFMA GEMM) kernels
    gemm_f32in<IN_DIM><<<ntiles, 256, 0, stream>>>(x, W1, as1, ad1, (uint2*)h8a, esa, eda, N);
    agg_mfma<false><<<aggGrid, 256, 0, stream>>>(h8a, esa, eda, rowptr, csrsrc, b1,
                                                 W2, as2, ad2, h8b, esb, edb, xbuf, N);
    agg_mfma<false><<<aggGrid, 256, 0, stream>>>(h8b, esb, edb, rowptr, csrsrc, b2,
                                                 W3, as3, ad3, h8a, esa, eda, xbuf, N);
    agg_mfma<false><<<aggGrid, 256, 0, stream>>>(h8a, esa, eda, rowptr, csrsrc, b3,
                                                 W4, as4, ad4, h8b, esb, edb, xbuf, N);
    agg_mfma<true> <<<aggGrid, 256, 0, stream>>>(h8b, esb, edb, rowptr, csrsrc, b4,
                                                 W4, as4, ad4, h8a, esa, eda, xbuf, N);

    // ---- global mean pool: one wave per graph ----
    pool_graph<<<(G * 64 + 255) / 256, 256, 0, stream>>>(xbuf, batch, (float*)d_out, N, G);
}

// Round 17
// 304.814 us; speedup vs baseline: 1.0938x; 1.0217x over previous
//
#include <hip/hip_runtime.h>
#include <hip/hip_fp16.h>

#define HDIM 32
#define IN_DIM 128
#define NEG_SLOPE 0.2f
#define NPB 128            // nodes per coarse bucket (power of 2)
#define NPB_SHIFT 7
#define MAXB 1024          // max buckets (B = ceil(N/128) = 782)
#define CHUNK 8192         // edges per chunk block
#define CAP 4096           // max records per bucket for LDS sort fast path

typedef _Float16 half8  __attribute__((ext_vector_type(8)));
typedef _Float16 half4v __attribute__((ext_vector_type(4)));
typedef float    floatx4 __attribute__((ext_vector_type(4)));
typedef float    floatx2 __attribute__((ext_vector_type(2)));

__device__ __forceinline__ float leaky(float e) {
    return (e >= 0.f) ? e : NEG_SLOPE * e;
}

// ------------- MFMA GEMM (layer 1, fp32 in): h8 fp8 + exact fp32 es/ed -----
// Epilogue stages C back into xs as fp16 (input rows dead after MFMA reads;
// within-wave program order makes read-before-write safe) — no fp32 stage.

template<int K>
__global__ __launch_bounds__(256) void gemm_f32in(
    const float* __restrict__ x, const float* __restrict__ W,
    const float* __restrict__ a_s, const float* __restrict__ a_d,
    uint2* __restrict__ h8, float* __restrict__ es, float* __restrict__ ed, int N)
{
    constexpr int KP = K + 8;
    __shared__ _Float16 xs[64 * KP];
    __shared__ _Float16 Wt[32 * KP];          // Wt[n][k] = W[k][n]
    const int tid = threadIdx.x;
    for (int i = tid; i < K * 32; i += 256) {
        int k = i >> 5, n = i & 31;
        Wt[n * KP + k] = (_Float16)W[i];
    }
    const int lane = tid & 63;
    const int wave = tid >> 6;
    const int m16  = lane & 15;
    const int quad = lane >> 4;
    const float as0 = a_s[m16], as1 = a_s[m16 + 16];
    const float ad0 = a_d[m16], ad1 = a_d[m16 + 16];

    const int ntiles = (N + 63) >> 6;
    for (int tile = blockIdx.x; tile < ntiles; tile += gridDim.x) {
        const int row0 = tile << 6;
        __syncthreads();
        for (int i = tid; i < 64 * (K / 4); i += 256) {
            int r  = i / (K / 4);
            int c4 = i % (K / 4);
            float4 v = (row0 + r < N) ? ((const float4*)x)[(size_t)(row0 + r) * (K / 4) + c4]
                                      : make_float4(0.f, 0.f, 0.f, 0.f);
            half4v hv = { (_Float16)v.x, (_Float16)v.y, (_Float16)v.z, (_Float16)v.w };
            *(half4v*)&xs[r * KP + c4 * 4] = hv;
        }
        __syncthreads();
        floatx4 acc0 = {0.f, 0.f, 0.f, 0.f}, acc1 = {0.f, 0.f, 0.f, 0.f};
        const int rbase = wave * 16;
        #pragma unroll
        for (int kt = 0; kt < K / 32; kt++) {
            half8 a  = *(half8*)&xs[(rbase + m16) * KP + kt * 32 + quad * 8];
            half8 b0 = *(half8*)&Wt[m16 * KP + kt * 32 + quad * 8];
            half8 b1 = *(half8*)&Wt[(m16 + 16) * KP + kt * 32 + quad * 8];
            acc0 = __builtin_amdgcn_mfma_f32_16x16x32_f16(a, b0, acc0, 0, 0, 0);
            acc1 = __builtin_amdgcn_mfma_f32_16x16x32_f16(a, b1, acc1, 0, 0, 0);
        }
        #pragma unroll
        for (int r = 0; r < 4; r++) {
            const int lr = rbase + quad * 4 + r;
            int row = row0 + lr;
            float c0 = acc0[r], c1 = acc1[r];
            xs[lr * KP + m16]      = (_Float16)c0;   // reuse xs as fp16 stage
            xs[lr * KP + m16 + 16] = (_Float16)c1;
            float ps = c0 * as0 + c1 * as1;
            float pd = c0 * ad0 + c1 * ad1;
            #pragma unroll
            for (int m = 8; m >= 1; m >>= 1) { ps += __shfl_xor(ps, m); pd += __shfl_xor(pd, m); }
            if (row < N && m16 == 0) { es[row] = ps; ed[row] = pd; }
        }
        __syncthreads();
        {   // pack fp8 from fp16 stage
            int r = tid >> 2, seg = tid & 3;
            int row = row0 + r;
            if (row < N) {
                const _Float16* sp = &xs[r * KP + seg * 8];
                half8 hv = *(const half8*)sp;
                unsigned int u0, u1;
                u0 = __builtin_amdgcn_cvt_pk_fp8_f32((float)hv[0], (float)hv[1], 0,  false);
                u0 = __builtin_amdgcn_cvt_pk_fp8_f32((float)hv[2], (float)hv[3], u0, true);
                u1 = __builtin_amdgcn_cvt_pk_fp8_f32((float)hv[4], (float)hv[5], 0,  false);
                u1 = __builtin_amdgcn_cvt_pk_fp8_f32((float)hv[6], (float)hv[7], u1, true);
                h8[(size_t)row * 4 + seg] = make_uint2(u0, u1);
            }
        }
    }
}

// ---------------- Two-level CSR build (once per call) ----------------

__global__ __launch_bounds__(256) void chunk_hist(
    const int* __restrict__ dsts, int E, int B, int* __restrict__ cnt2D)
{
    __shared__ int hist[MAXB];
    const int blk = blockIdx.x;
    for (int i = threadIdx.x; i < B; i += 256) hist[i] = 0;
    __syncthreads();
    const int e0 = blk * CHUNK;
    for (int i = threadIdx.x; i < CHUNK; i += 256) {
        int e = e0 + i;
        if (e < E) atomicAdd(&hist[dsts[e] >> NPB_SHIFT], 1);
    }
    __syncthreads();
    for (int i = threadIdx.x; i < B; i += 256) cnt2D[(size_t)blk * B + i] = hist[i];
}

__global__ __launch_bounds__(256) void chunk_scan(
    const int* __restrict__ cnt2D, int NBLK, int B,
    int* __restrict__ off2D, int* __restrict__ bcnt)
{
    __shared__ int s[256];
    const int b = blockIdx.x, t = threadIdx.x;
    int v = (t < NBLK) ? cnt2D[(size_t)t * B + b] : 0;
    s[t] = v;
    __syncthreads();
    for (int off = 1; off < 256; off <<= 1) {
        int add = (t >= off) ? s[t - off] : 0;
        __syncthreads();
        s[t] += add;
        __syncthreads();
    }
    if (t < NBLK) off2D[(size_t)t * B + b] = s[t] - v;
    if (t == 255) bcnt[b] = s[255];
}

__global__ __launch_bounds__(1024) void bucket_scan(
    const int* __restrict__ bcnt, int B, int E,
    int* __restrict__ bstart, int* __restrict__ rowptr, int N)
{
    __shared__ int s[1024];
    const int t = threadIdx.x;
    int v = (t < B) ? bcnt[t] : 0;
    s[t] = v;
    __syncthreads();
    for (int off = 1; off < 1024; off <<= 1) {
        int add = (t >= off) ? s[t - off] : 0;
        __syncthreads();
        s[t] += add;
        __syncthreads();
    }
    if (t < B) bstart[t] = s[t] - v;
    if (t == 0) { bstart[B] = E; rowptr[N] = E; }
}

__global__ __launch_bounds__(256) void pair_scatter2(
    const int* __restrict__ srcs, const int* __restrict__ dsts, int E, int B,
    const int* __restrict__ off2D, const int* __restrict__ bstart,
    int* __restrict__ pairs)
{
    __shared__ int cur[MAXB];
    const int blk = blockIdx.x;
    for (int i = threadIdx.x; i < B; i += 256)
        cur[i] = bstart[i] + off2D[(size_t)blk * B + i];
    __syncthreads();
    const int e0 = blk * CHUNK;
    for (int i = threadIdx.x; i < CHUNK; i += 256) {
        int e = e0 + i;
        if (e < E) {
            int s = srcs[e], d = dsts[e];
            int pos = atomicAdd(&cur[d >> NPB_SHIFT], 1);
            pairs[pos] = (s << NPB_SHIFT) | (d & (NPB - 1));
        }
    }
}

__global__ __launch_bounds__(256) void bucket_sort(
    const int* __restrict__ pairs, const int* __restrict__ bstart,
    int* __restrict__ rowptr, int* __restrict__ csrsrc, int N)
{
    __shared__ int ldeg[NPB];
    __shared__ int lex[NPB];
    __shared__ int recs[CAP];
    __shared__ int sorted[CAP];
    const int b = blockIdx.x, t = threadIdx.x;
    const int p0 = bstart[b], p1 = bstart[b + 1];
    const int cnt = p1 - p0;
    if (t < NPB) ldeg[t] = 0;
    __syncthreads();
    for (int i = t; i < cnt; i += 256) {
        int r = pairs[p0 + i];
        atomicAdd(&ldeg[r & (NPB - 1)], 1);
        if (i < CAP) recs[i] = r;
    }
    __syncthreads();
    if (t < NPB) lex[t] = ldeg[t];
    __syncthreads();
    for (int off = 1; off < NPB; off <<= 1) {
        int add = (t >= off && t < NPB) ? lex[t - off] : 0;
        __syncthreads();
        if (t < NPB) lex[t] += add;
        __syncthreads();
    }
    const int node0 = b * NPB;
    if (t < NPB) {
        int excl = lex[t] - ldeg[t];
        if (node0 + t < N) rowptr[node0 + t] = p0 + excl;
        ldeg[t] = excl;
    }
    __syncthreads();
    if (cnt <= CAP) {
        for (int i = t; i < cnt; i += 256) {
            int r = recs[i];
            int pos = atomicAdd(&ldeg[r & (NPB - 1)], 1);
            sorted[pos] = r >> NPB_SHIFT;
        }
        __syncthreads();
        for (int i = t; i < cnt; i += 256) csrsrc[p0 + i] = sorted[i];
    } else {
        for (int i = t; i < cnt; i += 256) {
            int r = pairs[p0 + i];
            int pos = atomicAdd(&ldeg[r & (NPB - 1)], 1);
            csrsrc[p0 + pos] = r >> NPB_SHIFT;
        }
    }
}

// -------- Fused agg + next-layer MFMA GEMM (low-LDS variant) ---------------
// 2 lanes/node, 128 nodes/block. Edge loop as R14-R16. For !LAST: out rows
// staged fp16 in xs, 32x32 MFMA GEMM, es/ed from fp32 accumulators, then the
// C tile is written BACK into xs as fp16 (input rows dead) and packed fp8.
// LDS = 12.8 KB (was 29.4) -> 7 blocks/CU instead of 5.

__device__ __forceinline__ void acc16(float* acc, uint4 u, float w) {
    floatx2 f0 = __builtin_amdgcn_cvt_pk_f32_fp8(u.x, false);
    floatx2 f1 = __builtin_amdgcn_cvt_pk_f32_fp8(u.x, true);
    floatx2 f2 = __builtin_amdgcn_cvt_pk_f32_fp8(u.y, false);
    floatx2 f3 = __builtin_amdgcn_cvt_pk_f32_fp8(u.y, true);
    floatx2 f4 = __builtin_amdgcn_cvt_pk_f32_fp8(u.z, false);
    floatx2 f5 = __builtin_amdgcn_cvt_pk_f32_fp8(u.z, true);
    floatx2 f6 = __builtin_amdgcn_cvt_pk_f32_fp8(u.w, false);
    floatx2 f7 = __builtin_amdgcn_cvt_pk_f32_fp8(u.w, true);
    acc[0]  += w * f0.x; acc[1]  += w * f0.y; acc[2]  += w * f1.x; acc[3]  += w * f1.y;
    acc[4]  += w * f2.x; acc[5]  += w * f2.y; acc[6]  += w * f3.x; acc[7]  += w * f3.y;
    acc[8]  += w * f4.x; acc[9]  += w * f4.y; acc[10] += w * f5.x; acc[11] += w * f5.y;
    acc[12] += w * f6.x; acc[13] += w * f6.y; acc[14] += w * f7.x; acc[15] += w * f7.y;
}

template<bool LAST>
__global__ __launch_bounds__(256) void agg_mfma(
    const uint4* __restrict__ h8in, const float* __restrict__ es, const float* __restrict__ ed,
    const int* __restrict__ rowptr, const int* __restrict__ csrsrc,
    const float* __restrict__ b,
    const float* __restrict__ Wn, const float* __restrict__ as_n, const float* __restrict__ ad_n,
    uint4* __restrict__ h8out, float* __restrict__ es_out, float* __restrict__ ed_out,
    float* __restrict__ out, int N)
{
    constexpr int KP = 40;                    // 32 + 8 pad
    __shared__ _Float16 xs[128 * KP];         // 10 KB: out rows, then C tile
    __shared__ _Float16 Wt[32 * KP];          // 2.5 KB
    const int tid = threadIdx.x;
    if (!LAST) {
        for (int i = tid; i < 32 * 32; i += 256) {
            int k = i >> 5, n = i & 31;
            Wt[n * KP + k] = (_Float16)Wn[i];
        }
    }
    const int node0 = blockIdx.x * 128;
    const int li    = tid >> 1;
    const int node  = node0 + li;
    const int l     = tid & 1;
    const bool valid = node < N;

    float acc[16];
    #pragma unroll
    for (int i = 0; i < 16; i++) acc[i] = 0.f;
    float den = 0.f;
    float o[16];

    if (valid) {
        const int e0 = rowptr[node];
        const int e1 = rowptr[node + 1];
        const float edi = ed[node];
        int e = e0;
        for (; e + 8 <= e1; e += 8) {
            int s[8]; float q[8]; uint4 u[8];
            #pragma unroll
            for (int j = 0; j < 8; j++) s[j] = csrsrc[e + j];
            #pragma unroll
            for (int j = 0; j < 8; j++) q[j] = es[s[j]];
            #pragma unroll
            for (int j = 0; j < 8; j++) u[j] = h8in[(size_t)s[j] * 2 + l];
            #pragma unroll
            for (int j = 0; j < 8; j++) {
                float w = __expf(leaky(q[j] + edi));
                den += w;
                acc16(acc, u[j], w);
            }
        }
        for (; e < e1; e++) {
            int s = csrsrc[e];
            float w = __expf(leaky(es[s] + edi));
            uint4 u = h8in[(size_t)s * 2 + l];
            den += w;
            acc16(acc, u, w);
        }
        {   // self-loop
            float w = __expf(leaky(es[node] + edi));
            uint4 u = h8in[(size_t)node * 2 + l];
            den += w;
            acc16(acc, u, w);
        }
        const float4* b4 = (const float4*)b;
        float inv = 1.f / den;
        #pragma unroll
        for (int g = 0; g < 4; g++) {
            float4 bv = b4[l * 4 + g];
            o[g*4+0] = acc[g*4+0] * inv + bv.x;
            o[g*4+1] = acc[g*4+1] * inv + bv.y;
            o[g*4+2] = acc[g*4+2] * inv + bv.z;
            o[g*4+3] = acc[g*4+3] * inv + bv.w;
        }
    }

    if (LAST) {
        if (valid) {
            float4* op = (float4*)out + (size_t)node * 8 + l * 4;
            #pragma unroll
            for (int g = 0; g < 4; g++) {
                float4 v = { o[g*4+0], o[g*4+1], o[g*4+2], o[g*4+3] };
                op[g] = v;
            }
        }
        return;
    }

    // stage out rows fp16 in LDS (zeros for invalid rows)
    {
        _Float16* xp = &xs[li * KP + l * 16];
        half8 v0, v1;
        if (valid) {
            v0 = (half8){ (_Float16)o[0], (_Float16)o[1], (_Float16)o[2], (_Float16)o[3],
                          (_Float16)o[4], (_Float16)o[5], (_Float16)o[6], (_Float16)o[7] };
            v1 = (half8){ (_Float16)o[8], (_Float16)o[9], (_Float16)o[10], (_Float16)o[11],
                          (_Float16)o[12], (_Float16)o[13], (_Float16)o[14], (_Float16)o[15] };
        } else {
            v0 = (half8)(_Float16)0.f;
            v1 = (half8)(_Float16)0.f;
        }
        *(half8*)xp = v0;
        *(half8*)(xp + 8) = v1;
    }
    __syncthreads();

    // block-level MFMA: h' = out @ Wn; C written back into xs as fp16.
    // Each wave reads/writes only its own 32-row range; within-wave program
    // order guarantees the a-reads complete before the C-writes.
    {
        const int lane = tid & 63, wave = tid >> 6;
        const int m16 = lane & 15, quad = lane >> 4;
        const float as0 = as_n[m16], as1 = as_n[m16 + 16];
        const float ad0 = ad_n[m16], ad1 = ad_n[m16 + 16];
        half8 a0v = *(half8*)&xs[(wave * 32 + m16) * KP + quad * 8];
        half8 a1v = *(half8*)&xs[(wave * 32 + 16 + m16) * KP + quad * 8];
        half8 b0 = *(half8*)&Wt[m16 * KP + quad * 8];
        half8 b1 = *(half8*)&Wt[(m16 + 16) * KP + quad * 8];
        #pragma unroll
        for (int rt = 0; rt < 2; rt++) {
            const int rb = wave * 32 + rt * 16;
            half8 a = (rt == 0) ? a0v : a1v;
            floatx4 c0 = {0.f,0.f,0.f,0.f}, c1 = {0.f,0.f,0.f,0.f};
            c0 = __builtin_amdgcn_mfma_f32_16x16x32_f16(a, b0, c0, 0, 0, 0);
            c1 = __builtin_amdgcn_mfma_f32_16x16x32_f16(a, b1, c1, 0, 0, 0);
            #pragma unroll
            for (int r = 0; r < 4; r++) {
                const int lr = rb + quad * 4 + r;
                int row = node0 + lr;
                float v0 = c0[r], v1 = c1[r];
                xs[lr * KP + m16]      = (_Float16)v0;
                xs[lr * KP + m16 + 16] = (_Float16)v1;
                float ps = v0 * as0 + v1 * as1;
                float pd = v0 * ad0 + v1 * ad1;
                #pragma unroll
                for (int m = 8; m >= 1; m >>= 1) { ps += __shfl_xor(ps, m); pd += __shfl_xor(pd, m); }
                if (row < N && m16 == 0) { es_out[row] = ps; ed_out[row] = pd; }
            }
        }
    }
    __syncthreads();

    // pack fp8: 256 threads -> 128 rows x 2 segs of 16 fp16 values (uint4)
    {
        int r = tid >> 1, seg = tid & 1;
        int row = node0 + r;
        if (row < N) {
            const _Float16* sp = &xs[r * KP + seg * 16];
            half8 hv0 = *(const half8*)sp;
            half8 hv1 = *(const half8*)(sp + 8);
            unsigned int u0, u1, u2, u3;
            u0 = __builtin_amdgcn_cvt_pk_fp8_f32((float)hv0[0], (float)hv0[1], 0,  false);
            u0 = __builtin_amdgcn_cvt_pk_fp8_f32((float)hv0[2], (float)hv0[3], u0, true);
            u1 = __builtin_amdgcn_cvt_pk_fp8_f32((float)hv0[4], (float)hv0[5], 0,  false);
            u1 = __builtin_amdgcn_cvt_pk_fp8_f32((float)hv0[6], (float)hv0[7], u1, true);
            u2 = __builtin_amdgcn_cvt_pk_fp8_f32((float)hv1[0], (float)hv1[1], 0,  false);
            u2 = __builtin_amdgcn_cvt_pk_fp8_f32((float)hv1[2], (float)hv1[3], u2, true);
            u3 = __builtin_amdgcn_cvt_pk_fp8_f32((float)hv1[4], (float)hv1[5], 0,  false);
            u3 = __builtin_amdgcn_cvt_pk_fp8_f32((float)hv1[6], (float)hv1[7], u3, true);
            uint4 v = { u0, u1, u2, u3 };
            h8out[(size_t)row * 2 + seg] = v;
        }
    }
}

// -------- Pool: one 64-lane wave per graph (batch sorted, binary search) ---

__global__ __launch_bounds__(256) void pool_graph(
    const float* __restrict__ x, const int* __restrict__ batch,
    float* __restrict__ out, int N, int G)
{
    const int g = (blockIdx.x * 256 + threadIdx.x) >> 6;
    if (g >= G) return;
    const int lane = threadIdx.x & 63;
    const int feat = lane & 31;
    const int half = lane >> 5;

    int lo = 0, hi = N;
    while (lo < hi) { int mid = (lo + hi) >> 1; if (batch[mid] < g) lo = mid + 1; else hi = mid; }
    const int start = lo;
    int lo2 = start, hi2 = N;
    while (lo2 < hi2) { int mid = (lo2 + hi2) >> 1; if (batch[mid] < g + 1) lo2 = mid + 1; else hi2 = mid; }
    const int end = lo2;

    float acc = 0.f;
    for (int i = start + half; i < end; i += 2)
        acc += x[(size_t)i * HDIM + feat];
    acc += __shfl_xor(acc, 32);
    if (half == 0) {
        float cnt = (float)(end - start);
        out[(size_t)g * HDIM + feat] = acc / fmaxf(cnt, 1.f);
    }
}

// ---------------- Launch ----------------

extern "C" void kernel_launch(void* const* d_in, const int* in_sizes, int n_in,
                              void* d_out, int out_size, void* d_ws, size_t ws_size,
                              hipStream_t stream) {
    const float* x          = (const float*)d_in[0];
    const int*   edge_index = (const int*)d_in[1];
    const int*   batch      = (const int*)d_in[2];

    const int N = in_sizes[2];              // 100000
    const int E = in_sizes[1] / 2;          // 1600000
    const int G = out_size / HDIM;          // 2048
    const int B = (N + NPB - 1) / NPB;      // 782 buckets
    const int NBLK = (E + CHUNK - 1) / CHUNK;
    const int ntiles = (N + 63) / 64;

    const int* srcs = edge_index;
    const int* dsts = edge_index + E;

    // workspace layout (16B-aligned offsets)
    char* p = (char*)d_ws;
    uint4* h8a    = (uint4*)p; p += (size_t)N * 2 * sizeof(uint4);   // fp8 rows, 32 B
    uint4* h8b    = (uint4*)p; p += (size_t)N * 2 * sizeof(uint4);
    float* xbuf   = (float*)p; p += (size_t)N * HDIM * sizeof(float);
    float* esa    = (float*)p; p += (size_t)N * sizeof(float);
    float* eda    = (float*)p; p += (size_t)N * sizeof(float);
    float* esb    = (float*)p; p += (size_t)N * sizeof(float);
    float* edb    = (float*)p; p += (size_t)N * sizeof(float);
    int*   rowptr = (int*)p;   p += (size_t)(N + 1) * sizeof(int);
    p += 16 - ((size_t)p & 15);
    int*   csrsrc = (int*)p;   p += (size_t)E * sizeof(int);
    int*   pairs  = (int*)p;   p += (size_t)E * sizeof(int);
    int*   cnt2D  = (int*)p;   p += (size_t)NBLK * B * sizeof(int);
    int*   off2D  = (int*)p;   p += (size_t)NBLK * B * sizeof(int);
    int*   bcnt   = (int*)p;   p += (size_t)B * sizeof(int);
    int*   bstart = (int*)p;   p += (size_t)(B + 1) * sizeof(int);

    // ---- CSR build (once; same edge set for all 4 layers) ----
    chunk_hist  <<<NBLK, 256, 0, stream>>>(dsts, E, B, cnt2D);
    chunk_scan  <<<B, 256, 0, stream>>>(cnt2D, NBLK, B, off2D, bcnt);
    bucket_scan <<<1, 1024, 0, stream>>>(bcnt, B, E, bstart, rowptr, N);
    pair_scatter2<<<NBLK, 256, 0, stream>>>(srcs, dsts, E, B, off2D, bstart, pairs);
    bucket_sort <<<B, 256, 0, stream>>>(pairs, bstart, rowptr, csrsrc, N);

    const float* W1  = (const float*)d_in[3];
    const float* as1 = (const float*)d_in[4];
    const float* ad1 = (const float*)d_in[5];
    const float* b1  = (const float*)d_in[6];
    const float* W2  = (const float*)d_in[7];
    const float* as2 = (const float*)d_in[8];
    const float* ad2 = (const float*)d_in[9];
    const float* b2  = (const float*)d_in[10];
    const float* W3  = (const float*)d_in[11];
    const float* as3 = (const float*)d_in[12];
    const float* ad3 = (const float*)d_in[13];
    const float* b3  = (const float*)d_in[14];
    const float* W4  = (const float*)d_in[15];
    const float* as4 = (const float*)d_in[16];
    const float* ad4 = (const float*)d_in[17];
    const float* b4  = (const float*)d_in[18];

    const int aggGrid = (N + 127) / 128;

    // layer 1 GEMM, then 4 fused agg(+next-layer MFMA GEMM) kernels
    gemm_f32in<IN_DIM><<<ntiles, 256, 0, stream>>>(x, W1, as1, ad1, (uint2*)h8a, esa, eda, N);
    agg_mfma<false><<<aggGrid, 256, 0, stream>>>(h8a, esa, eda, rowptr, csrsrc, b1,
                                                 W2, as2, ad2, h8b, esb, edb, xbuf, N);
    agg_mfma<false><<<aggGrid, 256, 0, stream>>>(h8b, esb, edb, rowptr, csrsrc, b2,
                                                 W3, as3, ad3, h8a, esa, eda, xbuf, N);
    agg_mfma<false><<<aggGrid, 256, 0, stream>>>(h8a, esa, eda, rowptr, csrsrc, b3,
                                                 W4, as4, ad4, h8b, esb, edb, xbuf, N);
    agg_mfma<true> <<<aggGrid, 256, 0, stream>>>(h8b, esb, edb, rowptr, csrsrc, b4,
                                                 W4, as4, ad4, h8a, esa, eda, xbuf, N);

    // ---- global mean pool: one wave per graph ----
    pool_graph<<<(G * 64 + 255) / 256, 256, 0, stream>>>(xbuf, batch, (float*)d_out, N, G);
}